// Round 13
// baseline (590.082 us; speedup 1.0000x reference)
//
#include <hip/hip_runtime.h>
#include <hip/hip_fp16.h>
#include <cstdint>

#define T_STEPS 512
#define HDIM    256
#define ROWS    8
#define LN_EPS  1e-5f

typedef _Float16 half8   __attribute__((ext_vector_type(8)));
typedef _Float16 half4v  __attribute__((ext_vector_type(4)));
typedef _Float16 half2v  __attribute__((ext_vector_type(2)));
typedef __fp16   fp16x2  __attribute__((ext_vector_type(2)));   // cvt_pkrtz ret type
typedef float    float4v __attribute__((ext_vector_type(4)));
typedef float    float2v __attribute__((ext_vector_type(2)));
typedef int      int4v   __attribute__((ext_vector_type(4)));
typedef int      int2v   __attribute__((ext_vector_type(2)));

// R9: tile-split tail. R8b (573us) showed the anti-phase mechanism works but
// the tail was data-locked behind BOTH MFMA blocks (needs d11/d21). Split the
// finalization so tile0's outputs use ONLY blockA results (d10/d20) and
// tile1's only blockB (d11/d21): each lane finalizes 2 tile0 cols (e-split
// across sel via 2 DPP exchanges) then 2 tile1 cols. tail0 is then
// independent of blockB -> the scheduler interleaves its VALU into blockB's
// MFMA shadow (within-wave overlap, not just sibling luck). Same three
// product terms as R4/R8b (absmax 0.0039 verified R8b).
#if __has_builtin(__builtin_amdgcn_permlane32_swap)
#define HAS_PL32 1
#else
#define HAS_PL32 0
#endif
#if __has_builtin(__builtin_amdgcn_permlane16_swap)
#define HAS_PL16 1
#else
#define HAS_PL16 0
#endif

struct __align__(16) Smem {
  _Float16 Bp[2][4096];     // 16384 B packed B fragments (double-buffered)
  float    gb[10][268];     // 10720 B gb[v][n] = tanh(v*we+be)@W + bu + beta@W
  float    wg[260];         // 1040 B  gamma @ W (deferred-LN mu term)
  float    wb[260];         // 1040 B  beta @ W
  float    red[2][8][20];   // 1280 B  [buf][row][wv*2+{0:S,1:Sq}], 8 slots
  int      xi[8][516];      // 16512 B clamped x indices (+4 pad for quad reads)
};

__device__ __forceinline__ float tanh_fast(float x) {
  float e = __expf(2.0f * x);
  float r = __builtin_amdgcn_rcpf(e + 1.0f);
  return fmaf(-2.0f, r, 1.0f);
}
// lane l -> l^8 (rotate-by-8 within each 16-lane row == xor 8), pure VALU
__device__ __forceinline__ float dpp_ror8(float v) {
  return __int_as_float(__builtin_amdgcn_mov_dpp(__float_as_int(v), 0x128, 0xf, 0xf, true));
}
// lane l -> l^16 (within 32-lane half), LDS crossbar, conflict-free (verified R1/R4)
__device__ __forceinline__ float swz_xor16(float v) {
  return __int_as_float(__builtin_amdgcn_ds_swizzle(__float_as_int(v), 0x401F));
}
// v[l] + v[l^16] in every lane
__device__ __forceinline__ float sum_xor16(float v) {
#if HAS_PL16
  int2v r2 = __builtin_amdgcn_permlane16_swap(__float_as_int(v), __float_as_int(v), false, false);
  return __int_as_float(r2[0]) + __int_as_float(r2[1]);
#else
  return v + swz_xor16(v);
#endif
}
// v[l] + v[l^32] in every lane
__device__ __forceinline__ float sum_xor32(float v) {
#if HAS_PL32
  int2v r2 = __builtin_amdgcn_permlane32_swap(__float_as_int(v), __float_as_int(v), false, false);
  return __int_as_float(r2[0]) + __int_as_float(r2[1]);
#else
  return v + __shfl_xor(v, 32, 64);
#endif
}

__global__ __launch_bounds__(512, 1)
void rnn_scan_kernel(const float* __restrict__ x,
                     const float* __restrict__ we,  const float* __restrict__ be,
                     const float* __restrict__ Wu,  const float* __restrict__ bu,
                     const float* __restrict__ gma, const float* __restrict__ bta,
                     const float* __restrict__ Wo,  const float* __restrict__ bo,
                     float* __restrict__ out)
{
  __shared__ Smem sm;
  const int tid = threadIdx.x;
  const int wv  = tid >> 6;        // wave 0..7, owns n in [32*wv, 32*wv+32)
  const int l   = tid & 63;
  const int q   = l >> 4;
  const int m   = l & 15;
  const int sel = m >> 3;          // 0: lane's cols are hi-products; 1: lo
  const int r   = m & 7;           // batch row within tile
  const int r0  = blockIdx.x * ROWS;

  // ---- init 0: x -> clamped int indices in LDS (the ONLY x reads) ----
  for (int i = tid; i < ROWS * T_STEPS; i += 512) {
    const int rr = i >> 9, c = i & (T_STEPS - 1);
    int xv = (int)x[(size_t)(r0 + rr) * T_STEPS + c];
    xv = xv < 0 ? 0 : (xv > 9 ? 9 : xv);
    sm.xi[rr][c] = xv;
  }
  if (tid < ROWS) {                // 4-entry zero pad for the quad prefetch
    sm.xi[tid][512] = 0; sm.xi[tid][513] = 0;
    sm.xi[tid][514] = 0; sm.xi[tid][515] = 0;
  }

  // ---- init 1: embed-tanh table in (to-be-zeroed) Bp space ----
  float* et = reinterpret_cast<float*>(&sm.Bp[0][0]);   // 10240 B < 16384 B
  if (tid < HDIM) {
    const float wek = we[tid], bek = be[tid];
    #pragma unroll
    for (int v = 0; v < 10; ++v)
      et[v*HDIM + tid] = tanh_fast(fmaf((float)v, wek, bek));
  }
  __syncthreads();

  // ---- init 2: gb = et@W + bu ; wg = gamma@W ; wb = beta@W ----
  {
    const int g = tid >> 8;        // 0: v=0..4 + wg, 1: v=5..9 + wb
    const int n = tid & 255;
    float acc[5] = {0,0,0,0,0};
    float accx = 0.0f;
    const int vb = g * 5;
    for (int k = 0; k < HDIM; ++k) {
      const float wk = Wu[(size_t)k*HDIM + n];
      #pragma unroll
      for (int v = 0; v < 5; ++v) acc[v] = fmaf(et[(vb+v)*HDIM + k], wk, acc[v]);
      const float xk = g ? bta[k] : gma[k];
      accx = fmaf(xk, wk, accx);
    }
    const float bun = bu[n];
    #pragma unroll
    for (int v = 0; v < 5; ++v) sm.gb[vb+v][n] = acc[v] + bun;
    if (g == 0) sm.wg[n] = accx; else sm.wb[n] = accx;
  }
  __syncthreads();

  // ---- init 3: fold beta@W into gb; zero Bp (both bufs) and red ----
  if (tid < HDIM) {
    const float wbn = sm.wb[tid];
    #pragma unroll
    for (int v = 0; v < 10; ++v) sm.gb[v][tid] += wbn;
  }
  {
    uint32_t* p = reinterpret_cast<uint32_t*>(&sm.Bp[0][0]);
    for (int i = tid; i < 4096; i += 512) p[i] = 0u;      // 16 KB = both bufs
  }
  if (tid < 320) (&sm.red[0][0][0])[tid] = 0.0f;

  // ---- persistent W fragments: full K, this wave's two 16-wide n-tiles ----
  half8 Whi[2][8], Wlo[2][8];
  #pragma unroll
  for (int nt = 0; nt < 2; ++nt) {
    const int n = wv*32 + nt*16 + m;
    #pragma unroll
    for (int kt = 0; kt < 8; ++kt) {
      const int k0 = kt*32 + q*8;
      half8 hi, lo;
      #pragma unroll
      for (int j = 0; j < 8; ++j) {
        float v = Wu[(size_t)(k0 + j)*HDIM + n];           // L2-hot across blocks
        _Float16 h = (_Float16)v;
        hi[j] = h;
        lo[j] = (_Float16)((v - (float)h) * 2048.0f);
      }
      Whi[nt][kt] = hi; Wlo[nt][kt] = lo;
    }
  }
  // this lane finalizes cols {nb, nb+1} (tile0) and {nb+16, nb+17} (tile1), row r
  const int nb = wv*32 + q*4 + sel*2;
  const float2v gmr0 = *reinterpret_cast<const float2v*>(&gma[nb]);
  const float2v gmr1 = *reinterpret_cast<const float2v*>(&gma[nb + 16]);
  __syncthreads();                            // wg/gb/xi ready, buffers zeroed
  const float2v wgr0 = *reinterpret_cast<const float2v*>(&sm.wg[nb]);
  const float2v wgr1 = *reinterpret_cast<const float2v*>(&sm.wg[nb + 16]);

  const float c1 = 4.8828125e-4f;             // 2^-11
  const float* gbp = &sm.gb[0][nb];
  float4v th4;                                // last tanh outputs (epilogue)

  // per-lane constant LDS offsets (halves)
  const int rdoff = l * 8;                                         // B read base
  const int woff0 = wv*512 + (q>>1)*128 + r*8 + (q&1)*4 + sel*2;   // tile0 hi; lo +64; tile1 +256

  // x-index quad prefetch (one b128 per 4 steps) + gb bias cols one step ahead
  int4v xQ = *reinterpret_cast<const int4v*>(&sm.xi[r][0]);
  float2v gbv0_n = *reinterpret_cast<const float2v*>(gbp + xQ[0]*268);
  float2v gbv1_n = *reinterpret_cast<const float2v*>(gbp + xQ[0]*268 + 16);

  for (int k = 0; k < T_STEPS/4; ++k) {
    const int4v xQn = *reinterpret_cast<const int4v*>(&sm.xi[r][k*4 + 4]);
    #pragma unroll
    for (int e = 0; e < 4; ++e) {
      const int rb = e & 1, wb = rb ^ 1;

      // issue red chunk read NOW, consume in the stats block (latency hidden)
      const float4v pq = *reinterpret_cast<const float4v*>(&sm.red[rb][r][q*4]);

      const float2v gbv0 = gbv0_n, gbv1 = gbv1_n;  // bias cols for THIS step
      const int xv2 = (e < 3) ? xQ[e + 1] : xQn[0];   // compile-time select

      // hoist all B fragments into registers (static-indexed; rule #20 safe)
      const _Float16* pbB = &sm.Bp[rb][rdoff];
      half8 bfr[8];
      #pragma unroll
      for (int kt = 0; kt < 8; ++kt)
        bfr[kt] = *reinterpret_cast<const half8*>(pbB + kt*512);

      // ---- MFMA block A: tile0 chains (16 MFMAs) ----
      float4v d10, d20;
      d10 = 0.0f; d20 = 0.0f;
      __builtin_amdgcn_s_setprio(1);
      #pragma unroll
      for (int kt = 0; kt < 8; ++kt) {
        d10 = __builtin_amdgcn_mfma_f32_16x16x32_f16(Whi[0][kt], bfr[kt], d10, 0, 0, 0);
        d20 = __builtin_amdgcn_mfma_f32_16x16x32_f16(Wlo[0][kt], bfr[kt], d20, 0, 0, 0);
      }
      __builtin_amdgcn_s_setprio(0);

      // ---- stats block (independent VALU -> fills block A's shadow) ----
      gbv0_n = *reinterpret_cast<const float2v*>(gbp + xv2*268);
      gbv1_n = *reinterpret_cast<const float2v*>(gbp + xv2*268 + 16);
      float S  = pq[0] + pq[2];
      float Sq = pq[1] + pq[3];
      S  = sum_xor32(sum_xor16(S));
      Sq = sum_xor32(sum_xor16(Sq));
      const float mu  = S * (1.0f/256.0f);
      const float var = fmaf(Sq, 1.0f/256.0f, -mu*mu);
      const float rs  = __builtin_amdgcn_rsqf(var + LN_EPS);
      const float nrsmu = -rs * mu;
      const float rsc   = rs * c1;

      // ---- MFMA block B: tile1 chains (16 MFMAs) ----
      float4v d11, d21;
      d11 = 0.0f; d21 = 0.0f;
      __builtin_amdgcn_s_setprio(1);
      #pragma unroll
      for (int kt = 0; kt < 8; ++kt) {
        d11 = __builtin_amdgcn_mfma_f32_16x16x32_f16(Whi[1][kt], bfr[kt], d11, 0, 0, 0);
        d21 = __builtin_amdgcn_mfma_f32_16x16x32_f16(Wlo[1][kt], bfr[kt], d21, 0, 0, 0);
      }
      __builtin_amdgcn_s_setprio(0);

      float s = 0.0f, sq = 0.0f;

      // ---- tail0: tile0 outputs, depends ONLY on d10/d20 (block A) ----
      // sel=0 lane owns hi-col products: full for its 2 cols needs partner's
      // lo-product (rsc*d10[j]); it sends partner's hi terms for cols 2,3.
      {
        float own0 = sel ? rsc * d10[2] : fmaf(rs, d10[0], rsc * d20[0]);
        float own1 = sel ? rsc * d10[3] : fmaf(rs, d10[1], rsc * d20[1]);
        float snd0 = sel ? rsc * d10[0] : fmaf(rs, d10[2], rsc * d20[2]);
        float snd1 = sel ? rsc * d10[1] : fmaf(rs, d10[3], rsc * d20[3]);
        const float rcv0 = dpp_ror8(snd0);
        const float rcv1 = dpp_ror8(snd1);
        const float pre0 = own0 + rcv0 + fmaf(nrsmu, wgr0[0], gbv0[0]);
        const float pre1 = own1 + rcv1 + fmaf(nrsmu, wgr0[1], gbv0[1]);
        const float t0 = tanh_fast(pre0);
        const float t1 = tanh_fast(pre1);
        th4[0] = t0; th4[1] = t1;
        s += t0 + t1; sq = fmaf(t0, t0, fmaf(t1, t1, sq));
        const float g0 = t0 * gmr0[0], g1 = t1 * gmr0[1];
        const fp16x2 h01 = __builtin_amdgcn_cvt_pkrtz(g0, g1);
        const float r0f = (g0 - (float)h01[0]) * 2048.0f;
        const float r1f = (g1 - (float)h01[1]) * 2048.0f;
        const fp16x2 l01 = __builtin_amdgcn_cvt_pkrtz(r0f, r1f);
        half2v hi2, lo2;
        hi2[0] = (_Float16)h01[0]; hi2[1] = (_Float16)h01[1];
        lo2[0] = (_Float16)l01[0]; lo2[1] = (_Float16)l01[1];
        *reinterpret_cast<half2v*>(&sm.Bp[wb][woff0])      = hi2;
        *reinterpret_cast<half2v*>(&sm.Bp[wb][woff0 + 64]) = lo2;
      }

      // ---- tail1: tile1 outputs, depends on d11/d21 (block B) ----
      {
        float own0 = sel ? rsc * d11[2] : fmaf(rs, d11[0], rsc * d21[0]);
        float own1 = sel ? rsc * d11[3] : fmaf(rs, d11[1], rsc * d21[1]);
        float snd0 = sel ? rsc * d11[0] : fmaf(rs, d11[2], rsc * d21[2]);
        float snd1 = sel ? rsc * d11[1] : fmaf(rs, d11[3], rsc * d21[3]);
        const float rcv0 = dpp_ror8(snd0);
        const float rcv1 = dpp_ror8(snd1);
        const float pre0 = own0 + rcv0 + fmaf(nrsmu, wgr1[0], gbv1[0]);
        const float pre1 = own1 + rcv1 + fmaf(nrsmu, wgr1[1], gbv1[1]);
        const float t0 = tanh_fast(pre0);
        const float t1 = tanh_fast(pre1);
        th4[2] = t0; th4[3] = t1;
        s += t0 + t1; sq = fmaf(t0, t0, fmaf(t1, t1, sq));
        const float g0 = t0 * gmr1[0], g1 = t1 * gmr1[1];
        const fp16x2 h01 = __builtin_amdgcn_cvt_pkrtz(g0, g1);
        const float r0f = (g0 - (float)h01[0]) * 2048.0f;
        const float r1f = (g1 - (float)h01[1]) * 2048.0f;
        const fp16x2 l01 = __builtin_amdgcn_cvt_pkrtz(r0f, r1f);
        half2v hi2, lo2;
        hi2[0] = (_Float16)h01[0]; hi2[1] = (_Float16)h01[1];
        lo2[0] = (_Float16)l01[0]; lo2[1] = (_Float16)l01[1];
        *reinterpret_cast<half2v*>(&sm.Bp[wb][woff0 + 256])      = hi2;
        *reinterpret_cast<half2v*>(&sm.Bp[wb][woff0 + 256 + 64]) = lo2;
      }

      // full in-wave reduction: xor8 (DPP) + xor16 + xor32
      s  += dpp_ror8(s);  s  = sum_xor32(sum_xor16(s));
      sq += dpp_ror8(sq); sq = sum_xor32(sum_xor16(sq));
      if (l < 8) {
        float2v v2; v2[0] = s; v2[1] = sq;
        *reinterpret_cast<float2v*>(&sm.red[wb][l][wv*2]) = v2;
      }
      __syncthreads();                           // the ONLY barrier per step
    }
    xQ = xQn;
  }

  // ---- epilogue: final LN (stats in red[0]), h_final in gb space, out GEMM ----
  float mu, rs;
  {
    const float4v pq = *reinterpret_cast<const float4v*>(&sm.red[0][r][q*4]);
    float S  = pq[0] + pq[2];
    float Sq = pq[1] + pq[3];
    S  = sum_xor32(sum_xor16(S));
    Sq = sum_xor32(sum_xor16(Sq));
    mu = S * (1.0f/256.0f);
    const float var = fmaf(Sq, 1.0f/256.0f, -mu*mu);
    rs = __builtin_amdgcn_rsqf(var + LN_EPS);
  }
  float* hf = reinterpret_cast<float*>(&sm.gb[0][0]);   // gb dead after loop
  {
    const float2v bt0 = *reinterpret_cast<const float2v*>(&bta[nb]);
    const float2v bt1 = *reinterpret_cast<const float2v*>(&bta[nb + 16]);
    float2v h0, h1;
    #pragma unroll
    for (int j = 0; j < 2; ++j) {
      h0[j] = fmaf((th4[j]     - mu) * rs, gmr0[j], bt0[j]);
      h1[j] = fmaf((th4[2 + j] - mu) * rs, gmr1[j], bt1[j]);
    }
    *reinterpret_cast<float2v*>(&hf[r*260 + nb])      = h0;
    *reinterpret_cast<float2v*>(&hf[r*260 + nb + 16]) = h1;
  }
  __syncthreads();
  if (tid < ROWS*10) {
    const int rr = tid / 10, o = tid % 10;
    float acc = bo[o];
    #pragma unroll 4
    for (int n = 0; n < HDIM; ++n)
      acc = fmaf(hf[rr*260 + n], Wo[n*10 + o], acc);
    out[(size_t)(r0 + rr)*10 + o] = acc;
  }
}

extern "C" void kernel_launch(void* const* d_in, const int* in_sizes, int n_in,
                              void* d_out, int out_size, void* d_ws, size_t ws_size,
                              hipStream_t stream) {
  const float* x  = (const float*)d_in[0];
  const float* we = (const float*)d_in[1];
  const float* be = (const float*)d_in[2];
  const float* Wu = (const float*)d_in[3];
  const float* bu = (const float*)d_in[4];
  const float* ga = (const float*)d_in[5];
  const float* bt = (const float*)d_in[6];
  const float* Wo = (const float*)d_in[7];
  const float* bo = (const float*)d_in[8];
  const int B = in_sizes[0] / T_STEPS;          // 2048
  dim3 grid(B / ROWS), block(512);
  rnn_scan_kernel<<<grid, block, 0, stream>>>(x, we, be, Wu, bu, ga, bt, Wo, bo,
                                              (float*)d_out);
}